// Round 1
// baseline (246.125 us; speedup 1.0000x reference)
//
#include <hip/hip_runtime.h>
#include <math.h>

#define Bq 4
#define Hh 8
#define Lh 2048
#define Dh 64
#define BH (Bq*Hh)

// ---------------- Kernel A: M[b,h,q] = max_s(dot) - sum_s(dot)/L ----------------
// 4 lanes per query; each group reads K rows as whole 64B lines (coalesced).
// XCD swizzle: block bi -> xcd=bi&7 handles bh in [4*xcd, 4*xcd+4) -> 2MB K per XCD L2.
__global__ __launch_bounds__(256) void kA_M(const float* __restrict__ Q,
                                            const float* __restrict__ K,
                                            const int* __restrict__ idxs,
                                            float* __restrict__ M, int u) {
    int bi = blockIdx.x;
    int xcd = bi & 7, slot = bi >> 3;          // slot 0..127
    int bh  = xcd * 4 + (slot >> 5);           // 0..31
    int qt  = slot & 31;                       // query tile 0..31 (64 q each)
    int tid = threadIdx.x;
    int wave = tid >> 6, lane = tid & 63;
    int g = lane >> 2, c = lane & 3;           // 16 groups x 4 lanes
    int q = qt * 64 + wave * 16 + g;           // 0..2047
    long gq = (long)bh * Lh + q;

    const float* qrow = Q + gq * Dh;
    float4 qf[4];
#pragma unroll
    for (int jj = 0; jj < 4; ++jj)
        qf[jj] = *(const float4*)(qrow + jj * 16 + c * 4);

    const float* kbase = K + (long)bh * Lh * Dh;
    const int* irow = idxs + q * u;
    float mx = -INFINITY, sm = 0.f;
    for (int s = 0; s < u; ++s) {
        int ki = irow[s];
        const float* krow = kbase + (long)ki * Dh;
        float acc = 0.f;
#pragma unroll
        for (int jj = 0; jj < 4; ++jj) {
            float4 kf = *(const float4*)(krow + jj * 16 + c * 4);
            acc += qf[jj].x * kf.x + qf[jj].y * kf.y + qf[jj].z * kf.z + qf[jj].w * kf.w;
        }
        acc += __shfl_xor(acc, 1);
        acc += __shfl_xor(acc, 2);   // full dot in all 4 lanes of the group
        mx = fmaxf(mx, acc);
        sm += acc;
    }
    if (c == 0) M[gq] = mx - sm * (1.0f / (float)Lh);
}

// ---------------- Kernel B: top-U indices of M per (b,h) ----------------
__global__ __launch_bounds__(256) void kB_topk(const float* __restrict__ M,
                                               int* __restrict__ topk, int U) {
    int bh = blockIdx.x;
    int tid = threadIdx.x;
    const float* m = M + (long)bh * Lh;
    float v[8];
#pragma unroll
    for (int j = 0; j < 8; ++j) v[j] = m[tid + 256 * j];

    __shared__ float rv[4];
    __shared__ int   ri[4];
    __shared__ int   bsel;
    int wave = tid >> 6, lane = tid & 63;

    for (int r = 0; r < U; ++r) {
        float lv = -INFINITY; int li = 0x7fffffff;
#pragma unroll
        for (int j = 0; j < 8; ++j) {
            int qi = tid + 256 * j;
            if ((v[j] > lv) || (v[j] == lv && qi < li)) { lv = v[j]; li = qi; }
        }
#pragma unroll
        for (int off = 1; off < 64; off <<= 1) {
            float ov = __shfl_xor(lv, off);
            int   oi = __shfl_xor(li, off);
            if ((ov > lv) || (ov == lv && oi < li)) { lv = ov; li = oi; }
        }
        if (lane == 0) { rv[wave] = lv; ri[wave] = li; }
        __syncthreads();
        if (tid == 0) {
            float bv = rv[0]; int bj = ri[0];
            for (int w = 1; w < 4; ++w)
                if ((rv[w] > bv) || (rv[w] == bv && ri[w] < bj)) { bv = rv[w]; bj = ri[w]; }
            bsel = bj;
            topk[bh * U + r] = bj;
        }
        __syncthreads();
        int bj = bsel;
#pragma unroll
        for (int j = 0; j < 8; ++j)
            if (bj == tid + 256 * j) v[j] = -INFINITY;
        __syncthreads();
    }
}

// ---------------- Kernel C: V column partial sums (8 chunks of 256 rows) ----------------
__global__ __launch_bounds__(256) void kC_vpart(const float* __restrict__ V,
                                                float* __restrict__ vpart) {
    int bi = blockIdx.x;
    int xcd = bi & 7, slot = bi >> 3;          // 0..31
    int bh = xcd * 4 + (slot >> 3);
    int chunk = slot & 7;
    int tid = threadIdx.x;
    int d = tid & 63, r0 = tid >> 6;
    const float* vb = V + ((long)bh * Lh + chunk * 256) * Dh;
    float s = 0.f;
    for (int i = 0; i < 64; ++i) s += vb[(r0 + 4 * i) * Dh + d];
    __shared__ float part[4][64];
    part[r0][d] = s;
    __syncthreads();
    if (tid < 64) {
        float t = part[0][tid] + part[1][tid] + part[2][tid] + part[3][tid];
        vpart[(bh * 8 + chunk) * 64 + tid] = t;
    }
}

// ---------------- Kernel E: fill context with broadcast V-mean ----------------
__global__ __launch_bounds__(256) void kE_fill(const float* __restrict__ vpart,
                                               float* __restrict__ ctx) {
    int tid = threadIdx.x;
    long base = (long)blockIdx.x * 1024;       // floats
    int bh = (int)(base >> 17);                // /131072
    __shared__ float vm[64];
    if (tid < 64) {
        float s = 0.f;
#pragma unroll
        for (int c2 = 0; c2 < 8; ++c2) s += vpart[(bh * 8 + c2) * 64 + tid];
        vm[tid] = s * (1.0f / (float)Lh);
    }
    __syncthreads();
    float4 val = *(const float4*)(vm + ((tid * 4) & 63));
    *(float4*)(ctx + base + tid * 4) = val;
}

// ---------------- Kernel D: attention for selected queries (flash-style) ----------------
// Block = (bh, u-chunk of 8 queries). 64-key tiles staged in LDS.
// Score mapping: wave ug owns queries {2ug, 2ug+1}; lane = key -> online-softmax
// stats stay wave-internal (register-only m/l).
#define TK 64
__global__ __launch_bounds__(256) void kD_attn(const float* __restrict__ Q,
                                               const float* __restrict__ K,
                                               const float* __restrict__ V,
                                               const int* __restrict__ topk,
                                               float* __restrict__ ctx,
                                               int U, int nch) {
    int bi = blockIdx.x;
    int xcd = bi & 7, slot = bi >> 3;          // slot 0..4*nch-1
    int bh = xcd * 4 + slot / nch;
    int uc = slot % nch;

    int tid = threadIdx.x;
    int wv = tid >> 6, lane = tid & 63;

    __shared__ float Qs[8 * 64];
    __shared__ float Ks[TK * 68];              // pad 68 breaks stride-64 bank alias
    __shared__ float Vs[TK * 64];
    __shared__ float Ps[8 * 68];
    __shared__ float alph[8], lst[8];
    __shared__ int   qidxs[8];
    __shared__ float accbuf[1024];

    if (tid < 8) {
        int gu = uc * 8 + tid;
        qidxs[tid] = (gu < U) ? topk[bh * U + gu] : 0;
    }
    __syncthreads();
    // load 8 scaled Q rows (fold 1/sqrt(D) into Q)
#pragma unroll
    for (int step = 0; step < 2; ++step) {
        int uu = step * 4 + wv;
        int row = qidxs[uu];
        Qs[uu * 64 + lane] = Q[((long)bh * Lh + row) * Dh + lane] * 0.125f;
    }
    __syncthreads();

    int kq = tid & 63;                 // score phase: key within tile
    int ug = tid >> 6;                 // wave -> u-pair
    float mrun0 = -INFINITY, mrun1 = -INFINITY;
    float lrun0 = 0.f, lrun1 = 0.f;
    // PV mapping: (u, d4, k-half)
    int pu = (tid >> 4) & 7, pd4 = tid & 15, kh = tid >> 7;
    float4 acc = {0.f, 0.f, 0.f, 0.f};

    const long kvbase = (long)bh * Lh * Dh;
    const float4* Kg4 = (const float4*)(K + kvbase);
    const float4* Vg4 = (const float4*)(V + kvbase);

    for (int t0 = 0; t0 < Lh; t0 += TK) {
        // ---- stage K,V tile (coalesced) ----
        int f40 = t0 * (Dh / 4);
#pragma unroll
        for (int j = 0; j < 4; ++j) {
            int i = tid + 256 * j;             // 0..1023 float4s
            float4 kv = Kg4[f40 + i];
            int row = i >> 4, col = i & 15;
            *(float4*)(&Ks[row * 68 + col * 4]) = kv;
            float4 vv = Vg4[f40 + i];
            *(float4*)(&Vs[i * 4]) = vv;
        }
        __syncthreads();

        // ---- scores for u = 2ug, 2ug+1 at key kq ----
        float s0 = 0.f, s1 = 0.f;
#pragma unroll
        for (int j16 = 0; j16 < 16; ++j16) {
            float4 kf = *(const float4*)(&Ks[kq * 68 + j16 * 4]);
            float4 qa = *(const float4*)(&Qs[(2 * ug + 0) * 64 + j16 * 4]);
            float4 qb = *(const float4*)(&Qs[(2 * ug + 1) * 64 + j16 * 4]);
            s0 += kf.x * qa.x + kf.y * qa.y + kf.z * qa.z + kf.w * qa.w;
            s1 += kf.x * qb.x + kf.y * qb.y + kf.z * qb.z + kf.w * qb.w;
        }
        // ---- wave-internal online softmax stats ----
        float m0 = s0, m1 = s1;
#pragma unroll
        for (int off = 1; off < 64; off <<= 1) {
            m0 = fmaxf(m0, __shfl_xor(m0, off));
            m1 = fmaxf(m1, __shfl_xor(m1, off));
        }
        float mn0 = fmaxf(mrun0, m0), mn1 = fmaxf(mrun1, m1);
        float a0 = __expf(mrun0 - mn0), a1 = __expf(mrun1 - mn1);
        float p0 = __expf(s0 - mn0),  p1 = __expf(s1 - mn1);
        float ls0 = p0, ls1 = p1;
#pragma unroll
        for (int off = 1; off < 64; off <<= 1) {
            ls0 += __shfl_xor(ls0, off);
            ls1 += __shfl_xor(ls1, off);
        }
        lrun0 = a0 * lrun0 + ls0;  lrun1 = a1 * lrun1 + ls1;
        mrun0 = mn0;               mrun1 = mn1;
        Ps[(2 * ug + 0) * 68 + kq] = p0;
        Ps[(2 * ug + 1) * 68 + kq] = p1;
        if (lane == 0) { alph[2 * ug] = a0; alph[2 * ug + 1] = a1; }
        __syncthreads();

        // ---- PV: acc[u][d4] over this tile's 64 keys (split over kh) ----
        float av = alph[pu];
        acc.x *= av; acc.y *= av; acc.z *= av; acc.w *= av;
#pragma unroll
        for (int k4 = 0; k4 < 8; ++k4) {
            int kk = kh * 32 + k4 * 4;
            float4 pf = *(const float4*)(&Ps[pu * 68 + kk]);
            float4 v0 = *(const float4*)(&Vs[(kk + 0) * 64 + pd4 * 4]);
            float4 v1 = *(const float4*)(&Vs[(kk + 1) * 64 + pd4 * 4]);
            float4 v2 = *(const float4*)(&Vs[(kk + 2) * 64 + pd4 * 4]);
            float4 v3 = *(const float4*)(&Vs[(kk + 3) * 64 + pd4 * 4]);
            acc.x += pf.x * v0.x + pf.y * v1.x + pf.z * v2.x + pf.w * v3.x;
            acc.y += pf.x * v0.y + pf.y * v1.y + pf.z * v2.y + pf.w * v3.y;
            acc.z += pf.x * v0.z + pf.y * v1.z + pf.z * v2.z + pf.w * v3.z;
            acc.w += pf.x * v0.w + pf.y * v1.w + pf.z * v2.w + pf.w * v3.w;
        }
        __syncthreads();   // protect Ks/Vs/Ps before next stage
    }

    if (lane == 0) { lst[2 * ug] = lrun0; lst[2 * ug + 1] = lrun1; }
    *(float4*)(&accbuf[tid * 4]) = acc;
    __syncthreads();
    if (tid < 128) {
        int u = tid >> 4, d4 = tid & 15;
        int gu = uc * 8 + u;
        if (gu < U) {
            float4 x0 = *(const float4*)(&accbuf[tid * 4]);
            float4 x1 = *(const float4*)(&accbuf[(tid + 128) * 4]);
            float inv = 1.0f / lst[u];
            int row = qidxs[u];
            float4 o;
            o.x = (x0.x + x1.x) * inv; o.y = (x0.y + x1.y) * inv;
            o.z = (x0.z + x1.z) * inv; o.w = (x0.w + x1.w) * inv;
            *(float4*)(ctx + ((long)bh * Lh + row) * Dh + d4 * 4) = o;
        }
    }
}

extern "C" void kernel_launch(void* const* d_in, const int* in_sizes, int n_in,
                              void* d_out, int out_size, void* d_ws, size_t ws_size,
                              hipStream_t stream) {
    const float* Q    = (const float*)d_in[0];
    const float* K    = (const float*)d_in[1];
    const float* V    = (const float*)d_in[2];
    const int*   idxs = (const int*)d_in[3];
    float* ctx = (float*)d_out;

    int u = in_sizes[3] / Lh;    // 40 for this instance
    int U = u;                   // U_part == u here (same formula, caps inactive)
    int nch = (U + 7) / 8;       // u-chunks for kD

    // workspace layout (floats)
    float* wsf   = (float*)d_ws;
    float* M     = wsf;                        // 65536 f
    int*   topk  = (int*)(wsf + BH * Lh);      // up to 2048 ints reserved
    float* vpart = wsf + BH * Lh + 2048;       // 32*8*64 f

    kA_M   <<<1024,       256, 0, stream>>>(Q, K, idxs, M, u);
    kC_vpart<<<256,       256, 0, stream>>>(V, vpart);
    kB_topk<<<BH,         256, 0, stream>>>(M, topk, U);
    kE_fill<<<4096,       256, 0, stream>>>(vpart, ctx);
    kD_attn<<<BH * nch,   256, 0, stream>>>(Q, K, V, topk, ctx, U, nch);
}

// Round 2
// 167.244 us; speedup vs baseline: 1.4717x; 1.4717x over previous
//
#include <hip/hip_runtime.h>
#include <math.h>

#define Bq 4
#define Hh 8
#define Lh 2048
#define Dh 64
#define BH (Bq*Hh)

// ---------------- Kernel A: M[b,h,q] = max_s(dot) - sum_s(dot)/L ----------------
// 4 lanes per query; batched int4 index prefetch + 2 K-row gathers in flight.
__global__ __launch_bounds__(256) void kA_M(const float* __restrict__ Q,
                                            const float* __restrict__ K,
                                            const int* __restrict__ idxs,
                                            float* __restrict__ M, int u) {
    int bi = blockIdx.x;
    int xcd = bi & 7, slot = bi >> 3;          // slot 0..127
    int bh  = xcd * 4 + (slot >> 5);           // 0..31
    int qt  = slot & 31;                       // query tile 0..31 (64 q each)
    int tid = threadIdx.x;
    int wave = tid >> 6, lane = tid & 63;
    int g = lane >> 2, c = lane & 3;           // 16 groups x 4 lanes
    int q = qt * 64 + wave * 16 + g;           // 0..2047
    long gq = (long)bh * Lh + q;

    const float* qrow = Q + gq * Dh;
    float4 qf[4];
#pragma unroll
    for (int jj = 0; jj < 4; ++jj)
        qf[jj] = *(const float4*)(qrow + jj * 16 + c * 4);

    const float* kbase = K + (long)bh * Lh * Dh;
    const int* irow = idxs + q * u;            // 160B-aligned for u%4==0
    float mx = -INFINITY, sm = 0.f;
    int s = 0;
    for (; s + 4 <= u; s += 4) {
        int4 ki = *(const int4*)(irow + s);
        // pair 1
        {
            const float* k0 = kbase + (long)ki.x * Dh + c * 4;
            const float* k1 = kbase + (long)ki.y * Dh + c * 4;
            float4 kf0[4], kf1[4];
#pragma unroll
            for (int jj = 0; jj < 4; ++jj) { kf0[jj] = *(const float4*)(k0 + jj * 16);
                                             kf1[jj] = *(const float4*)(k1 + jj * 16); }
            float a0 = 0.f, a1 = 0.f;
#pragma unroll
            for (int jj = 0; jj < 4; ++jj) {
                a0 += qf[jj].x*kf0[jj].x + qf[jj].y*kf0[jj].y + qf[jj].z*kf0[jj].z + qf[jj].w*kf0[jj].w;
                a1 += qf[jj].x*kf1[jj].x + qf[jj].y*kf1[jj].y + qf[jj].z*kf1[jj].z + qf[jj].w*kf1[jj].w;
            }
            a0 += __shfl_xor(a0, 1); a0 += __shfl_xor(a0, 2);
            a1 += __shfl_xor(a1, 1); a1 += __shfl_xor(a1, 2);
            mx = fmaxf(mx, fmaxf(a0, a1)); sm += a0 + a1;
        }
        // pair 2
        {
            const float* k0 = kbase + (long)ki.z * Dh + c * 4;
            const float* k1 = kbase + (long)ki.w * Dh + c * 4;
            float4 kf0[4], kf1[4];
#pragma unroll
            for (int jj = 0; jj < 4; ++jj) { kf0[jj] = *(const float4*)(k0 + jj * 16);
                                             kf1[jj] = *(const float4*)(k1 + jj * 16); }
            float a0 = 0.f, a1 = 0.f;
#pragma unroll
            for (int jj = 0; jj < 4; ++jj) {
                a0 += qf[jj].x*kf0[jj].x + qf[jj].y*kf0[jj].y + qf[jj].z*kf0[jj].z + qf[jj].w*kf0[jj].w;
                a1 += qf[jj].x*kf1[jj].x + qf[jj].y*kf1[jj].y + qf[jj].z*kf1[jj].z + qf[jj].w*kf1[jj].w;
            }
            a0 += __shfl_xor(a0, 1); a0 += __shfl_xor(a0, 2);
            a1 += __shfl_xor(a1, 1); a1 += __shfl_xor(a1, 2);
            mx = fmaxf(mx, fmaxf(a0, a1)); sm += a0 + a1;
        }
    }
    for (; s < u; ++s) {
        int ki = irow[s];
        const float* krow = kbase + (long)ki * Dh + c * 4;
        float acc = 0.f;
#pragma unroll
        for (int jj = 0; jj < 4; ++jj) {
            float4 kf = *(const float4*)(krow + jj * 16);
            acc += qf[jj].x*kf.x + qf[jj].y*kf.y + qf[jj].z*kf.z + qf[jj].w*kf.w;
        }
        acc += __shfl_xor(acc, 1);
        acc += __shfl_xor(acc, 2);
        mx = fmaxf(mx, acc); sm += acc;
    }
    if (c == 0) M[gq] = mx - sm * (1.0f / (float)Lh);
}

// ---------------- Kernel B: top-U via 4-level radix select ----------------
// One block per (b,h). Monotone float->uint key; find exact 40th-largest key T,
// then compact {key > T} plus r ties at T. Output order irrelevant (scatter).
__global__ __launch_bounds__(256) void kB_topk(const float* __restrict__ M,
                                               int* __restrict__ topk, int U) {
    int bh = blockIdx.x, tid = threadIdx.x;
    const float* m = M + (long)bh * Lh;
    unsigned key[8];
#pragma unroll
    for (int j = 0; j < 8; ++j) {
        unsigned ub = __float_as_uint(m[tid + 256 * j]);
        key[j] = ub ^ ((ub >> 31) ? 0xFFFFFFFFu : 0x80000000u);
    }
    __shared__ unsigned hist[256];
    __shared__ unsigned prefix_s;
    __shared__ int need_s;
    if (tid == 0) { prefix_s = 0u; need_s = U; }

    for (int level = 3; level >= 0; --level) {
        int shift = level * 8;
        hist[tid] = 0u;
        __syncthreads();
        unsigned prefix = prefix_s;
        int need = need_s;
        unsigned pmask = (level == 3) ? 0u : (0xFFFFFFFFu << (shift + 8));
#pragma unroll
        for (int j = 0; j < 8; ++j)
            if ((key[j] & pmask) == prefix)
                atomicAdd(&hist[(key[j] >> shift) & 0xFF], 1u);
        __syncthreads();
        if (tid < 64) {
            int lane = tid;
            unsigned h0 = hist[lane*4+0], h1 = hist[lane*4+1],
                     h2 = hist[lane*4+2], h3 = hist[lane*4+3];
            unsigned lt = h0 + h1 + h2 + h3;
            unsigned ssum = lt;            // inclusive suffix over lane totals
#pragma unroll
            for (int off = 1; off < 64; off <<= 1) {
                unsigned t = __shfl_down(ssum, off);
                if (lane + off < 64) ssum += t;
            }
            unsigned sx  = ssum - lt;      // suffix excl. this lane's bins
            unsigned suf3 = sx  + h3;
            unsigned suf2 = suf3 + h2;
            unsigned suf1 = suf2 + h1;
            unsigned suf0 = suf1 + h0;
            int localb = -1; unsigned nxt = 0u;
            if      ((int)suf3 >= need) { localb = lane*4+3; nxt = sx;   }
            else if ((int)suf2 >= need) { localb = lane*4+2; nxt = suf3; }
            else if ((int)suf1 >= need) { localb = lane*4+1; nxt = suf2; }
            else if ((int)suf0 >= need) { localb = lane*4+0; nxt = suf1; }
            unsigned long long ball = __ballot(localb >= 0);
            int hilane = 63 - __clzll(ball);   // largest b overall (suffix monotone)
            if (lane == hilane) {
                prefix_s = prefix | ((unsigned)localb << shift);
                need_s = need - (int)nxt;
            }
        }
        __syncthreads();
    }
    unsigned T = prefix_s;
    int r = need_s;                         // ties at T to take (==1 for distinct)
    __shared__ int cgt, ceq;
    if (tid == 0) { cgt = 0; ceq = 0; }
    __syncthreads();
    int* out = topk + bh * U;
#pragma unroll
    for (int j = 0; j < 8; ++j) {
        if (key[j] > T) { int p = atomicAdd(&cgt, 1); out[p] = tid + 256 * j; }
        else if (key[j] == T) { int e = atomicAdd(&ceq, 1); if (e < r) out[U - r + e] = tid + 256 * j; }
    }
}

// ---------------- Kernel C: V column partial sums (8 chunks of 256 rows) ----------------
__global__ __launch_bounds__(256) void kC_vpart(const float* __restrict__ V,
                                                float* __restrict__ vpart) {
    int bi = blockIdx.x;
    int xcd = bi & 7, slot = bi >> 3;          // 0..31
    int bh = xcd * 4 + (slot >> 3);
    int chunk = slot & 7;
    int tid = threadIdx.x;
    int d = tid & 63, r0 = tid >> 6;
    const float* vb = V + ((long)bh * Lh + chunk * 256) * Dh;
    float s = 0.f;
    for (int i = 0; i < 64; ++i) s += vb[(r0 + 4 * i) * Dh + d];
    __shared__ float part[4][64];
    part[r0][d] = s;
    __syncthreads();
    if (tid < 64) {
        float t = part[0][tid] + part[1][tid] + part[2][tid] + part[3][tid];
        vpart[(bh * 8 + chunk) * 64 + tid] = t;
    }
}

// ---------------- Kernel E: fill context with broadcast V-mean ----------------
__global__ __launch_bounds__(256) void kE_fill(const float* __restrict__ vpart,
                                               float* __restrict__ ctx) {
    int tid = threadIdx.x;
    long base = (long)blockIdx.x * 1024;       // floats
    int bh = (int)(base >> 17);                // /131072
    __shared__ float vm[64];
    if (tid < 64) {
        float s = 0.f;
#pragma unroll
        for (int c2 = 0; c2 < 8; ++c2) s += vpart[(bh * 8 + c2) * 64 + tid];
        vm[tid] = s * (1.0f / (float)Lh);
    }
    __syncthreads();
    float4 val = *(const float4*)(vm + ((tid * 4) & 63));
    *(float4*)(ctx + base + tid * 4) = val;
}

// ---------------- Kernel D: split-K partial attention ----------------
// Block = (bh, u-chunk of 8 queries, key-chunk of 256 keys). 4 tiles of 64 keys.
// Writes unnormalized (m, l, acc) partials to workspace.
#define TK 64
__global__ __launch_bounds__(256) void kD_part(const float* __restrict__ Q,
                                               const float* __restrict__ K,
                                               const float* __restrict__ V,
                                               const int* __restrict__ topk,
                                               float* __restrict__ pm,
                                               float* __restrict__ pl,
                                               float* __restrict__ pacc,
                                               int U, int nch) {
    int bi = blockIdx.x;
    int xcd = bi & 7, slot = bi >> 3;          // 0 .. 4*nch*8-1
    int per = nch * 8;
    int bh = xcd * 4 + slot / per;
    int rest = slot % per;
    int uc = rest >> 3, kc = rest & 7;

    int tid = threadIdx.x;
    int wv = tid >> 6, lane = tid & 63;

    __shared__ float Qs[8 * 64];
    __shared__ float Ks[TK * 68];              // pad 68 breaks stride-64 bank alias
    __shared__ float Vs[TK * 64];
    __shared__ float Ps[8 * 68];
    __shared__ float alph[8], mst[8], lst[8];
    __shared__ int   qidxs[8];
    float* accbuf = Ks;                        // alias: safe after final loop barrier

    if (tid < 8) {
        int gu = uc * 8 + tid;
        qidxs[tid] = (gu < U) ? topk[bh * U + gu] : 0;
    }
    __syncthreads();
#pragma unroll
    for (int step = 0; step < 2; ++step) {
        int uu = step * 4 + wv;
        int row = qidxs[uu];
        Qs[uu * 64 + lane] = Q[((long)bh * Lh + row) * Dh + lane] * 0.125f;
    }
    __syncthreads();

    int kq = tid & 63;                 // score phase: key within tile
    int ug = tid >> 6;                 // wave -> u-pair
    float mrun0 = -INFINITY, mrun1 = -INFINITY;
    float lrun0 = 0.f, lrun1 = 0.f;
    int pu = (tid >> 4) & 7, pd4 = tid & 15, kh = tid >> 7;
    float4 acc = {0.f, 0.f, 0.f, 0.f};

    const long kvbase = (long)bh * Lh * Dh;
    const float4* Kg4 = (const float4*)(K + kvbase);
    const float4* Vg4 = (const float4*)(V + kvbase);
    int kbase0 = kc * 256;

    for (int t0 = 0; t0 < 256; t0 += TK) {
        int f40 = (kbase0 + t0) * (Dh / 4);
#pragma unroll
        for (int j = 0; j < 4; ++j) {
            int i = tid + 256 * j;             // 0..1023 float4s
            float4 kv = Kg4[f40 + i];
            int row = i >> 4, col = i & 15;
            *(float4*)(&Ks[row * 68 + col * 4]) = kv;
            float4 vv = Vg4[f40 + i];
            *(float4*)(&Vs[i * 4]) = vv;
        }
        __syncthreads();

        // scores for u = 2ug, 2ug+1 at key kq
        float s0 = 0.f, s1 = 0.f;
#pragma unroll
        for (int j16 = 0; j16 < 16; ++j16) {
            float4 kf = *(const float4*)(&Ks[kq * 68 + j16 * 4]);
            float4 qa = *(const float4*)(&Qs[(2 * ug + 0) * 64 + j16 * 4]);
            float4 qb = *(const float4*)(&Qs[(2 * ug + 1) * 64 + j16 * 4]);
            s0 += kf.x * qa.x + kf.y * qa.y + kf.z * qa.z + kf.w * qa.w;
            s1 += kf.x * qb.x + kf.y * qb.y + kf.z * qb.z + kf.w * qb.w;
        }
        float m0 = s0, m1 = s1;
#pragma unroll
        for (int off = 1; off < 64; off <<= 1) {
            m0 = fmaxf(m0, __shfl_xor(m0, off));
            m1 = fmaxf(m1, __shfl_xor(m1, off));
        }
        float mn0 = fmaxf(mrun0, m0), mn1 = fmaxf(mrun1, m1);
        float a0 = __expf(mrun0 - mn0), a1 = __expf(mrun1 - mn1);
        float p0 = __expf(s0 - mn0),  p1 = __expf(s1 - mn1);
        float ls0 = p0, ls1 = p1;
#pragma unroll
        for (int off = 1; off < 64; off <<= 1) {
            ls0 += __shfl_xor(ls0, off);
            ls1 += __shfl_xor(ls1, off);
        }
        lrun0 = a0 * lrun0 + ls0;  lrun1 = a1 * lrun1 + ls1;
        mrun0 = mn0;               mrun1 = mn1;
        Ps[(2 * ug + 0) * 68 + kq] = p0;
        Ps[(2 * ug + 1) * 68 + kq] = p1;
        if (lane == 0) { alph[2 * ug] = a0; alph[2 * ug + 1] = a1; }
        __syncthreads();

        // PV over this tile's 64 keys (split over kh)
        float av = alph[pu];
        acc.x *= av; acc.y *= av; acc.z *= av; acc.w *= av;
#pragma unroll
        for (int k4 = 0; k4 < 8; ++k4) {
            int kk = kh * 32 + k4 * 4;
            float4 pf = *(const float4*)(&Ps[pu * 68 + kk]);
            float4 v0 = *(const float4*)(&Vs[(kk + 0) * 64 + pd4 * 4]);
            float4 v1 = *(const float4*)(&Vs[(kk + 1) * 64 + pd4 * 4]);
            float4 v2 = *(const float4*)(&Vs[(kk + 2) * 64 + pd4 * 4]);
            float4 v3 = *(const float4*)(&Vs[(kk + 3) * 64 + pd4 * 4]);
            acc.x += pf.x * v0.x + pf.y * v1.x + pf.z * v2.x + pf.w * v3.x;
            acc.y += pf.x * v0.y + pf.y * v1.y + pf.z * v2.y + pf.w * v3.y;
            acc.z += pf.x * v0.z + pf.y * v1.z + pf.z * v2.z + pf.w * v3.z;
            acc.w += pf.x * v0.w + pf.y * v1.w + pf.z * v2.w + pf.w * v3.w;
        }
        __syncthreads();   // all waves done with Ks/Vs/Ps before next stage/epilogue
    }

    if (lane == 0) {
        mst[2 * ug] = mrun0; lst[2 * ug] = lrun0;
        mst[2 * ug + 1] = mrun1; lst[2 * ug + 1] = lrun1;
    }
    *(float4*)(&accbuf[tid * 4]) = acc;        // overwrites Ks (safe: post-barrier)
    __syncthreads();
    int pbase = ((bh * nch + uc) * 8);
    if (tid < 128) {
        int u = tid >> 4, d4 = tid & 15;
        float4 x0 = *(const float4*)(&accbuf[tid * 4]);
        float4 x1 = *(const float4*)(&accbuf[(tid + 128) * 4]);
        float4 o;
        o.x = x0.x + x1.x; o.y = x0.y + x1.y;
        o.z = x0.z + x1.z; o.w = x0.w + x1.w;
        *(float4*)(pacc + ((long)(pbase + u) * 8 + kc) * 64 + d4 * 4) = o;
    }
    if (tid < 8) {
        int qp = (pbase + tid) * 8 + kc;
        pm[qp] = mst[tid];
        pl[qp] = lst[tid];
    }
}

// ---------------- Kernel F: combine split-K partials, scatter to ctx ----------------
__global__ __launch_bounds__(256) void kF_comb(const float* __restrict__ pm,
                                               const float* __restrict__ pl,
                                               const float* __restrict__ pacc,
                                               const int* __restrict__ topk,
                                               float* __restrict__ ctx,
                                               int U, int nch) {
    int bi = blockIdx.x;                       // 0 .. 32*nch-1
    int bh = bi / nch, uc = bi % nch;
    int tid = threadIdx.x;
    int u = tid >> 5, t = tid & 31;
    int gu = uc * 8 + u;
    if (gu >= U) return;
    int qbase = (bh * nch + uc) * 8 + u;       // partial row group
    float m[8], l[8];
#pragma unroll
    for (int kc = 0; kc < 8; ++kc) { m[kc] = pm[qbase * 8 + kc]; l[kc] = pl[qbase * 8 + kc]; }
    float gm = m[0];
#pragma unroll
    for (int kc = 1; kc < 8; ++kc) gm = fmaxf(gm, m[kc]);
    float w[8]; float gl = 0.f;
#pragma unroll
    for (int kc = 0; kc < 8; ++kc) { w[kc] = __expf(m[kc] - gm); gl += l[kc] * w[kc]; }
    float inv = 1.0f / gl;
    float o0 = 0.f, o1 = 0.f;
#pragma unroll
    for (int kc = 0; kc < 8; ++kc) {
        const float* a = pacc + ((long)qbase * 8 + kc) * 64;
        o0 += a[t] * w[kc];
        o1 += a[t + 32] * w[kc];
    }
    int row = topk[bh * U + gu];
    float* crow = ctx + ((long)bh * Lh + row) * Dh;
    crow[t]      = o0 * inv;
    crow[t + 32] = o1 * inv;
}

extern "C" void kernel_launch(void* const* d_in, const int* in_sizes, int n_in,
                              void* d_out, int out_size, void* d_ws, size_t ws_size,
                              hipStream_t stream) {
    const float* Q    = (const float*)d_in[0];
    const float* K    = (const float*)d_in[1];
    const float* V    = (const float*)d_in[2];
    const int*   idxs = (const int*)d_in[3];
    float* ctx = (float*)d_out;

    int u = in_sizes[3] / Lh;    // 40
    int U = u;
    int nch = (U + 7) / 8;       // 5

    // workspace layout (floats)
    float* wsf   = (float*)d_ws;
    float* M     = wsf;                          // 65536
    int*   topk  = (int*)(wsf + 65536);          // 2048 slots
    float* vpart = wsf + 65536 + 2048;           // 16384
    float* pm    = wsf + 83968;                  // 32*nch*8*8 = 10240
    float* pl    = pm + 32 * nch * 8 * 8;        // 10240
    float* pacc  = pl + 32 * nch * 8 * 8;        // 10240*64

    kA_M    <<<1024,           256, 0, stream>>>(Q, K, idxs, M, u);
    kC_vpart<<<256,            256, 0, stream>>>(V, vpart);
    kB_topk <<<BH,             256, 0, stream>>>(M, topk, U);
    kE_fill <<<4096,           256, 0, stream>>>(vpart, ctx);
    kD_part <<<BH * nch * 8,   256, 0, stream>>>(Q, K, V, topk, pm, pl, pacc, U, nch);
    kF_comb <<<BH * nch,       256, 0, stream>>>(pm, pl, pacc, topk, ctx, U, nch);
}